// Round 12
// baseline (524.136 us; speedup 1.0000x reference)
//
#include <hip/hip_runtime.h>
#include <cstdint>
#include <cstddef>

#define NFEAT 128
#define TGRAPH 10
#define NGRAPHS 512
#define BN_EPS 1e-5f
#define BIN_CHUNK 2048
#define PAD 16  // stride (in elements) for hot atomic counters: one cacheline each

typedef __attribute__((ext_vector_type(8))) short bf16x8;
typedef __attribute__((ext_vector_type(4))) float f32x4;

__device__ __forceinline__ float bf2f(short s) {
    union { unsigned u; float f; } c;
    c.u = ((unsigned)(unsigned short)s) << 16;
    return c.f;
}
__device__ __forceinline__ short f2bf(float f) {
    union { float f; unsigned u; } c;
    c.f = f;
    unsigned u = c.u;
    return (short)((u + 0x7fffu + ((u >> 16) & 1u)) >> 16);
}
__device__ __forceinline__ void acc2(float& a, float& b, unsigned v) {
    union { unsigned u; float f; } lo, hi;
    lo.u = v << 16;
    hi.u = v & 0xffff0000u;
    a += lo.f;
    b += hi.f;
}

// A-frag memory layout (shorts): buffer of 16-row tiles; element (row, k) lives at
//   ((row>>4)*4 + (k>>5))*512 + (((k>>3)&3)*16 + (row&15))*8 + (k&7)

// ---------------- CSR build, bucket-local (bucket = dst>>9, <=256 buckets) ----------------
__global__ __launch_bounds__(256) void k_bucket_hist(const int* __restrict__ dst,
                                                     int* __restrict__ bhist, int E) {
    __shared__ int h[256];
    int t = threadIdx.x;
    h[t] = 0;
    __syncthreads();
    for (int e = blockIdx.x * blockDim.x + t; e < E; e += gridDim.x * blockDim.x)
        atomicAdd(&h[dst[e] >> 9], 1);
    __syncthreads();
    if (h[t]) atomicAdd(&bhist[t * PAD], h[t]);  // padded: one line per counter
}

__global__ void k_bucket_scan(const int* __restrict__ bhist, int* __restrict__ bbase,
                              int* __restrict__ cur256, int E) {
    __shared__ int s[256];
    int t = threadIdx.x;
    int v = bhist[t * PAD];
    s[t] = v;
    __syncthreads();
    for (int off = 1; off < 256; off <<= 1) {
        int x = 0;
        if (t >= off) x = s[t - off];
        __syncthreads();
        if (t >= off) s[t] += x;
        __syncthreads();
    }
    int excl = s[t] - v;
    bbase[t] = excl;
    cur256[t * PAD] = excl;  // padded cursor
    if (t == 255) bbase[256] = E;
}

__global__ __launch_bounds__(256) void k_bin_scatter(const int* __restrict__ src,
                                                     const int* __restrict__ dst,
                                                     int* __restrict__ cur256,
                                                     int2* __restrict__ binned, int E) {
    __shared__ int hist[256];
    __shared__ int base[256];
    int t = threadIdx.x;
    int e0 = blockIdx.x * BIN_CHUNK;
    int e1 = min(e0 + BIN_CHUNK, E);
    hist[t] = 0;
    __syncthreads();
    for (int e = e0 + t; e < e1; e += 256) {
        int b = dst[e] >> 9;
        atomicAdd(&hist[b], 1);
    }
    __syncthreads();
    int c = hist[t];
    if (c > 0) base[t] = atomicAdd(&cur256[t * PAD], c);  // padded: parallel across lines
    __syncthreads();
    hist[t] = 0;
    __syncthreads();
    for (int e = e0 + t; e < e1; e += 256) {
        int d = dst[e];
        int b = d >> 9;
        int loc = atomicAdd(&hist[b], 1);
        binned[base[b] + loc] = make_int2(src[e], d);
    }
}

__global__ __launch_bounds__(512) void k_bucket_csr(const int2* __restrict__ binned,
                                                    const int* __restrict__ bbase,
                                                    int* __restrict__ rowptr,
                                                    int* __restrict__ adj,
                                                    int N, int E, int nb) {
    __shared__ int deg[512];
    __shared__ int cur[512];
    int b = blockIdx.x;
    int t = threadIdx.x;
    int e0 = bbase[b], e1 = bbase[b + 1];
    deg[t] = 0;
    __syncthreads();
    for (int e = e0 + t; e < e1; e += 512)
        atomicAdd(&deg[binned[e].y & 511], 1);
    __syncthreads();
    int v = deg[t];
    for (int off = 1; off < 512; off <<= 1) {
        int x = 0;
        if (t >= off) x = deg[t - off];
        __syncthreads();
        if (t >= off) deg[t] += x;
        __syncthreads();
    }
    int excl = deg[t] - v;
    cur[t] = excl;
    int node = b * 512 + t;
    if (node < N) rowptr[node] = e0 + excl;
    if (b == nb - 1 && t == 0) rowptr[N] = E;
    __syncthreads();
    for (int e = e0 + t; e < e1; e += 512) {
        int2 p = binned[e];
        int loc = atomicAdd(&cur[p.y & 511], 1);
        adj[e0 + loc] = p.x;
    }
}

// ---------------- fused fp32->bf16 convert (x) + weight frag prep ----------------
__global__ void k_prep(const float* __restrict__ x, short* __restrict__ xbf,
                       const float* __restrict__ W0, const float* __restrict__ W1,
                       const float* __restrict__ W2, const float* __restrict__ W3,
                       short* __restrict__ Wf, int n4) {
    int i = blockIdx.x * blockDim.x + threadIdx.x;
    if (i < n4) {
        float4 v = ((const float4*)x)[i];
        ushort4 o;
        o.x = (unsigned short)f2bf(v.x);
        o.y = (unsigned short)f2bf(v.y);
        o.z = (unsigned short)f2bf(v.z);
        o.w = (unsigned short)f2bf(v.w);
        ((ushort4*)xbf)[i] = o;
    } else {
        int idx = i - n4;
        if (idx < 4 * 16384) {
            int w = idx >> 14, r = idx & 16383;
            int j = r & 7, lane = (r >> 3) & 63, ct = (r >> 9) & 7, kc = r >> 12;
            int k = kc * 32 + (lane >> 4) * 8 + j;
            int n = ct * 16 + (lane & 15);
            const float* W = (w == 0) ? W0 : (w == 1) ? W1 : (w == 2) ? W2 : W3;
            Wf[idx] = f2bf(W[k * NFEAT + n]);
        }
    }
}

// ---------------- aggregation (bf16), dwordx4 gathers, A-frag-layout output ----------
__global__ __launch_bounds__(256) void k_aggregate_v4(const short* __restrict__ X,
                                                      const int* __restrict__ rowptr,
                                                      const int* __restrict__ adj,
                                                      short* __restrict__ XA, int N) {
    int tid = threadIdx.x;
    int lane = tid & 63;
    int g = lane >> 4;
    int p = lane & 15;
    int wid = (blockIdx.x * blockDim.x + tid) >> 6;
    if (wid >= N) return;
    const uint4* Xv = (const uint4*)X;  // one row = 16 uint4
    float acc[8];
#pragma unroll
    for (int j = 0; j < 8; j++) acc[j] = 0.f;
    int r0 = rowptr[wid], r1 = rowptr[wid + 1];
    for (int e = r0; e < r1; e += 8) {
        int e0 = e + g, e1 = e + 4 + g;
        uint4 v0 = {0u, 0u, 0u, 0u}, v1 = {0u, 0u, 0u, 0u};
        if (e0 < r1) v0 = Xv[(size_t)adj[e0] * 16 + p];
        if (e1 < r1) v1 = Xv[(size_t)adj[e1] * 16 + p];
        acc2(acc[0], acc[1], v0.x);
        acc2(acc[2], acc[3], v0.y);
        acc2(acc[4], acc[5], v0.z);
        acc2(acc[6], acc[7], v0.w);
        acc2(acc[0], acc[1], v1.x);
        acc2(acc[2], acc[3], v1.y);
        acc2(acc[4], acc[5], v1.z);
        acc2(acc[6], acc[7], v1.w);
    }
#pragma unroll
    for (int j = 0; j < 8; j++) {
        acc[j] += __shfl_xor(acc[j], 16);
        acc[j] += __shfl_xor(acc[j], 32);
    }
    if (g == 0) {
        uint4 sv = Xv[(size_t)wid * 16 + p];
        acc2(acc[0], acc[1], sv.x);
        acc2(acc[2], acc[3], sv.y);
        acc2(acc[4], acc[5], sv.z);
        acc2(acc[6], acc[7], sv.w);
        uint4 o;
        o.x = (unsigned)(unsigned short)f2bf(acc[0]) | ((unsigned)(unsigned short)f2bf(acc[1]) << 16);
        o.y = (unsigned)(unsigned short)f2bf(acc[2]) | ((unsigned)(unsigned short)f2bf(acc[3]) << 16);
        o.z = (unsigned)(unsigned short)f2bf(acc[4]) | ((unsigned)(unsigned short)f2bf(acc[5]) << 16);
        o.w = (unsigned)(unsigned short)f2bf(acc[6]) | ((unsigned)(unsigned short)f2bf(acc[7]) << 16);
        size_t dst = ((size_t)(wid >> 4) * 4 + (p >> 2)) * 512 +
                     (size_t)(((p & 3) * 16 + (wid & 15)) * 8);
        *(uint4*)(XA + dst) = o;
    }
}

// ---------------- MFMA GEMM: direct frag loads; stats atomics padded ----------------
template <bool BN_RELU_IN, bool RELU_OUT, bool STATS, bool FRAG_OUT>
__global__ __launch_bounds__(256) void k_gemm_mfma(const short* __restrict__ A,
                                                   const short* __restrict__ Wf,
                                                   const float* __restrict__ bias,
                                                   float* __restrict__ stats,
                                                   const float* __restrict__ gamma,
                                                   const float* __restrict__ beta,
                                                   short* __restrict__ C, int N) {
    __shared__ float s_aux[256];  // STATS: sum|sq ; BN: scale|shift
    int tid = threadIdx.x;
    int wave = tid >> 6, lane = tid & 63;
    int quad = lane >> 4, l16 = lane & 15;
    int row_base = blockIdx.x * 128 + wave * 32;

    if constexpr (STATS) {
        s_aux[tid] = 0.f;
        __syncthreads();
    }
    if constexpr (BN_RELU_IN) {
        if (tid < NFEAT) {
            float mean = stats[tid * PAD] / (float)N;
            float var = stats[(NFEAT + tid) * PAD] / (float)N - mean * mean;
            float inv = rsqrtf(var + BN_EPS);
            float sc = gamma[tid] * inv;
            s_aux[tid] = sc;
            s_aux[NFEAT + tid] = beta[tid] - mean * sc;
        }
        __syncthreads();
    }

    f32x4 acc[2][8];
#pragma unroll
    for (int i = 0; i < 2; i++)
#pragma unroll
        for (int j = 0; j < 8; j++) acc[i][j] = (f32x4){0.f, 0.f, 0.f, 0.f};

    const short* af = A + ((size_t)(blockIdx.x * 8 + wave * 2) * 4) * 512;

#pragma unroll
    for (int kc = 0; kc < 4; ++kc) {
        bf16x8 a0 = *(const bf16x8*)(af + (size_t)kc * 512 + lane * 8);
        bf16x8 a1 = *(const bf16x8*)(af + (size_t)(4 + kc) * 512 + lane * 8);
        if constexpr (BN_RELU_IN) {
            int koff = kc * 32 + quad * 8;
#pragma unroll
            for (int j = 0; j < 8; j++) {
                float sc = s_aux[koff + j];
                float sh = s_aux[NFEAT + koff + j];
                a0[j] = f2bf(fmaxf(bf2f(a0[j]) * sc + sh, 0.f));
                a1[j] = f2bf(fmaxf(bf2f(a1[j]) * sc + sh, 0.f));
            }
        }
        const short* wp = Wf + ((size_t)(kc * 8) * 64 + lane) * 8;
#pragma unroll
        for (int ct = 0; ct < 8; ++ct) {
            bf16x8 b = *(const bf16x8*)(wp + (size_t)ct * 64 * 8);
            acc[0][ct] = __builtin_amdgcn_mfma_f32_16x16x32_bf16(a0, b, acc[0][ct], 0, 0, 0);
            acc[1][ct] = __builtin_amdgcn_mfma_f32_16x16x32_bf16(a1, b, acc[1][ct], 0, 0, 0);
        }
    }

    // C/D layout: col = lane&15 (+16*ct), row = quad*4 + reg (+16*rt)
#pragma unroll
    for (int ct = 0; ct < 8; ++ct) {
        int col = ct * 16 + l16;
        float bv = bias[col];
        float ls = 0.f, ls2 = 0.f;
#pragma unroll
        for (int rt = 0; rt < 2; ++rt) {
#pragma unroll
            for (int reg = 0; reg < 4; ++reg) {
                int row = row_base + rt * 16 + quad * 4 + reg;
                if (row < N) {
                    float v = acc[rt][ct][reg] + bv;
                    if constexpr (RELU_OUT) v = fmaxf(v, 0.f);
                    if constexpr (FRAG_OUT) {
                        size_t addr = ((size_t)(row >> 4) * 4 + (col >> 5)) * 512 +
                                      (size_t)((((col >> 3) & 3) * 16 + (row & 15)) * 8 + (col & 7));
                        C[addr] = f2bf(v);
                    } else {
                        C[(size_t)row * NFEAT + col] = f2bf(v);
                    }
                    if constexpr (STATS) { ls += v; ls2 += v * v; }
                }
            }
        }
        if constexpr (STATS) {
            atomicAdd(&s_aux[col], ls);
            atomicAdd(&s_aux[NFEAT + col], ls2);
        }
    }

    if constexpr (STATS) {
        __syncthreads();
        if (tid < NFEAT) {
            atomicAdd(&stats[tid * PAD], s_aux[tid]);                    // padded
            atomicAdd(&stats[(NFEAT + tid) * PAD], s_aux[NFEAT + tid]);  // padded
        }
    }
}

// ---------------- node-parallel pooling (batch sorted; per-run register accum) ----------
__global__ __launch_bounds__(256) void k_pool2(const short* __restrict__ H2,
                                               const int* __restrict__ batch,
                                               float* __restrict__ pooled, int N) {
    int t = threadIdx.x;
    int c2 = t & 63;
    int rofs = t >> 6;
    int n0 = blockIdx.x * 128;
    int cur = -1;
    float ax = 0.f, ay = 0.f;
    for (int i = 0; i < 32; ++i) {
        int n = n0 + rofs + i * 4;
        if (n >= N) break;
        int g = batch[n];
        if (g != cur) {
            if (cur >= 0) {
                atomicAdd(&pooled[cur * NFEAT + c2 * 2], ax);
                atomicAdd(&pooled[cur * NFEAT + c2 * 2 + 1], ay);
            }
            cur = g; ax = 0.f; ay = 0.f;
        }
        unsigned v = *(const unsigned*)(H2 + (size_t)n * NFEAT + c2 * 2);
        ax += bf2f((short)(v & 0xffff));
        ay += bf2f((short)(v >> 16));
    }
    if (cur >= 0) {
        atomicAdd(&pooled[cur * NFEAT + c2 * 2], ax);
        atomicAdd(&pooled[cur * NFEAT + c2 * 2 + 1], ay);
    }
}

__global__ void k_final(const float* __restrict__ pooled, const float* __restrict__ Wl,
                        const float* __restrict__ bl, float* __restrict__ out) {
    int idx = blockIdx.x * blockDim.x + threadIdx.x;
    if (idx >= NGRAPHS * TGRAPH) return;
    int g = idx / TGRAPH, t = idx % TGRAPH;
    const float* p = pooled + (size_t)g * NFEAT;
    float acc = bl[t];
#pragma unroll 16
    for (int k = 0; k < NFEAT; ++k) acc += p[k] * Wl[k * TGRAPH + t];
    out[idx] = acc;
}

extern "C" void kernel_launch(void* const* d_in, const int* in_sizes, int n_in,
                              void* d_out, int out_size, void* d_ws, size_t ws_size,
                              hipStream_t stream) {
    const float* x = (const float*)d_in[0];
    const int* ei = (const int*)d_in[1];
    const int* batch = (const int*)d_in[2];
    const float* W1a = (const float*)d_in[3];
    const float* b1a = (const float*)d_in[4];
    const float* g1 = (const float*)d_in[5];
    const float* bt1 = (const float*)d_in[6];
    const float* W1b = (const float*)d_in[7];
    const float* b1b = (const float*)d_in[8];
    const float* W2a = (const float*)d_in[9];
    const float* b2a = (const float*)d_in[10];
    const float* g2 = (const float*)d_in[11];
    const float* bt2 = (const float*)d_in[12];
    const float* W2b = (const float*)d_in[13];
    const float* b2b = (const float*)d_in[14];
    const float* Wl = (const float*)d_in[15];
    const float* bl = (const float*)d_in[16];
    float* out = (float*)d_out;

    int N = in_sizes[2];
    int E = in_sizes[1] / 2;
    int nb = (N + 511) >> 9;
    const int* src = ei;
    const int* dst = ei + E;

    int gemmBlocks = (N + 127) / 128;
    int padRows = gemmBlocks * 128;

    char* ws = (char*)d_ws;
    size_t off = 0;
    auto alloc = [&](size_t bytes) -> void* {
        void* p = ws + off;
        off = (off + bytes + 255) & ~(size_t)255;
        return p;
    };
    short* xbf = (short*)alloc((size_t)N * NFEAT * 2);        // row-major (gather input)
    short* ag = (short*)alloc((size_t)padRows * NFEAT * 2);   // frag layout
    short* ybf = (short*)alloc((size_t)padRows * NFEAT * 2);  // frag layout
    short* hbf = (short*)alloc((size_t)N * NFEAT * 2);        // row-major (gather input)
    short* h2bf = (short*)alloc((size_t)N * NFEAT * 2);       // row-major (pool input)
    short* Wf = (short*)alloc((size_t)4 * 16384 * 2);
    int* adj = (int*)alloc((size_t)E * 4);
    int2* binned = (int2*)alloc((size_t)E * 8);
    int* rowptr = (int*)alloc((size_t)(N + 1) * 4);
    int* bbase = (int*)alloc(257 * 4);
    int* cur256 = (int*)alloc(256 * PAD * 4);
    // zero-region: bhist + stats1 + stats2 + pooled (all padded counters)
    int* bhist = (int*)alloc(256 * PAD * 4);
    float* stats1 = (float*)alloc(256 * PAD * 4);
    float* stats2 = (float*)alloc(256 * PAD * 4);
    float* pooled = (float*)alloc((size_t)NGRAPHS * NFEAT * 4);
    size_t zbytes = (char*)(pooled + (size_t)NGRAPHS * NFEAT) - (char*)bhist;

    hipMemsetAsync(bhist, 0, zbytes, stream);

    // ---- CSR build (bucket-local) ----
    k_bucket_hist<<<784, 256, 0, stream>>>(dst, bhist, E);
    k_bucket_scan<<<1, 256, 0, stream>>>(bhist, bbase, cur256, E);
    k_bin_scatter<<<(E + BIN_CHUNK - 1) / BIN_CHUNK, 256, 0, stream>>>(src, dst, cur256, binned, E);
    k_bucket_csr<<<nb, 512, 0, stream>>>(binned, bbase, rowptr, adj, N, E, nb);

    // ---- dtype prep (fused) ----
    int n4 = N * NFEAT / 4;
    int prepTot = n4 + 4 * 16384;
    k_prep<<<(prepTot + 255) / 256, 256, 0, stream>>>(x, xbf, W1a, W1b, W2a, W2b, Wf, n4);

    int aggBlocks = (N + 3) / 4;  // one wave per node

    // ---- layer 1 ----
    k_aggregate_v4<<<aggBlocks, 256, 0, stream>>>(xbf, rowptr, adj, ag, N);
    k_gemm_mfma<false, false, true, true><<<gemmBlocks, 256, 0, stream>>>(
        ag, Wf + 0 * 16384, b1a, stats1, nullptr, nullptr, ybf, N);
    k_gemm_mfma<true, true, false, false><<<gemmBlocks, 256, 0, stream>>>(
        ybf, Wf + 1 * 16384, b1b, stats1, g1, bt1, hbf, N);

    // ---- layer 2 ----
    k_aggregate_v4<<<aggBlocks, 256, 0, stream>>>(hbf, rowptr, adj, ag, N);
    k_gemm_mfma<false, false, true, true><<<gemmBlocks, 256, 0, stream>>>(
        ag, Wf + 2 * 16384, b2a, stats2, nullptr, nullptr, ybf, N);
    k_gemm_mfma<true, true, false, false><<<gemmBlocks, 256, 0, stream>>>(
        ybf, Wf + 3 * 16384, b2b, stats2, g2, bt2, h2bf, N);

    // ---- pooling + classifier ----
    k_pool2<<<(N + 127) / 128, 256, 0, stream>>>(h2bf, batch, pooled, N);
    k_final<<<(NGRAPHS * TGRAPH + 255) / 256, 256, 0, stream>>>(pooled, Wl, bl, out);
}

// Round 13
// 490.178 us; speedup vs baseline: 1.0693x; 1.0693x over previous
//
#include <hip/hip_runtime.h>
#include <cstdint>
#include <cstddef>

#define NFEAT 128
#define TGRAPH 10
#define NGRAPHS 512
#define BN_EPS 1e-5f
#define BIN_CHUNK 2048

typedef __attribute__((ext_vector_type(8))) short bf16x8;
typedef __attribute__((ext_vector_type(4))) float f32x4;

__device__ __forceinline__ float bf2f(short s) {
    union { unsigned u; float f; } c;
    c.u = ((unsigned)(unsigned short)s) << 16;
    return c.f;
}
__device__ __forceinline__ short f2bf(float f) {
    union { float f; unsigned u; } c;
    c.f = f;
    unsigned u = c.u;
    return (short)((u + 0x7fffu + ((u >> 16) & 1u)) >> 16);
}
__device__ __forceinline__ void acc2(float& a, float& b, unsigned v) {
    union { unsigned u; float f; } lo, hi;
    lo.u = v << 16;
    hi.u = v & 0xffff0000u;
    a += lo.f;
    b += hi.f;
}

// A-frag memory layout (shorts): buffer of 16-row tiles; element (row, k) lives at
//   ((row>>4)*4 + (k>>5))*512 + (((k>>3)&3)*16 + (row&15))*8 + (k&7)
// so GEMM lane (quad,l16) reads its bf16x8 at tilebase + kc*512 + lane*8 (1KB/instr coalesced).

// ---------------- CSR build, bucket-local (bucket = dst>>9, <=256 buckets) ----------------
__global__ __launch_bounds__(256) void k_bucket_hist(const int* __restrict__ dst,
                                                     int* __restrict__ bhist, int E) {
    __shared__ int h[256];
    int t = threadIdx.x;
    h[t] = 0;
    __syncthreads();
    for (int e = blockIdx.x * blockDim.x + t; e < E; e += gridDim.x * blockDim.x)
        atomicAdd(&h[dst[e] >> 9], 1);
    __syncthreads();
    if (h[t]) atomicAdd(&bhist[t], h[t]);
}

__global__ void k_bucket_scan(const int* __restrict__ bhist, int* __restrict__ bbase,
                              int* __restrict__ cur256, int E) {
    __shared__ int s[256];
    int t = threadIdx.x;
    int v = bhist[t];
    s[t] = v;
    __syncthreads();
    for (int off = 1; off < 256; off <<= 1) {
        int x = 0;
        if (t >= off) x = s[t - off];
        __syncthreads();
        if (t >= off) s[t] += x;
        __syncthreads();
    }
    int excl = s[t] - v;
    bbase[t] = excl;
    cur256[t] = excl;
    if (t == 255) bbase[256] = E;
}

__global__ __launch_bounds__(256) void k_bin_scatter(const int* __restrict__ src,
                                                     const int* __restrict__ dst,
                                                     int* __restrict__ cur256,
                                                     int2* __restrict__ binned, int E) {
    __shared__ int hist[256];
    __shared__ int base[256];
    int t = threadIdx.x;
    int e0 = blockIdx.x * BIN_CHUNK;
    int e1 = min(e0 + BIN_CHUNK, E);
    hist[t] = 0;
    __syncthreads();
    for (int e = e0 + t; e < e1; e += 256) {
        int b = dst[e] >> 9;
        atomicAdd(&hist[b], 1);
    }
    __syncthreads();
    int c = hist[t];
    if (c > 0) base[t] = atomicAdd(&cur256[t], c);
    __syncthreads();
    hist[t] = 0;
    __syncthreads();
    for (int e = e0 + t; e < e1; e += 256) {
        int d = dst[e];
        int b = d >> 9;
        int loc = atomicAdd(&hist[b], 1);
        binned[base[b] + loc] = make_int2(src[e], d);
    }
}

__global__ __launch_bounds__(512) void k_bucket_csr(const int2* __restrict__ binned,
                                                    const int* __restrict__ bbase,
                                                    int* __restrict__ rowptr,
                                                    int* __restrict__ adj,
                                                    int N, int E, int nb) {
    __shared__ int deg[512];
    __shared__ int cur[512];
    int b = blockIdx.x;
    int t = threadIdx.x;
    int e0 = bbase[b], e1 = bbase[b + 1];
    deg[t] = 0;
    __syncthreads();
    for (int e = e0 + t; e < e1; e += 512)
        atomicAdd(&deg[binned[e].y & 511], 1);
    __syncthreads();
    int v = deg[t];
    for (int off = 1; off < 512; off <<= 1) {
        int x = 0;
        if (t >= off) x = deg[t - off];
        __syncthreads();
        if (t >= off) deg[t] += x;
        __syncthreads();
    }
    int excl = deg[t] - v;
    cur[t] = excl;
    int node = b * 512 + t;
    if (node < N) rowptr[node] = e0 + excl;
    if (b == nb - 1 && t == 0) rowptr[N] = E;
    __syncthreads();
    for (int e = e0 + t; e < e1; e += 512) {
        int2 p = binned[e];
        int loc = atomicAdd(&cur[p.y & 511], 1);
        adj[e0 + loc] = p.x;
    }
}

// ---------------- fused fp32->bf16 convert (x) + weight frag prep ----------------
__global__ void k_prep(const float* __restrict__ x, short* __restrict__ xbf,
                       const float* __restrict__ W0, const float* __restrict__ W1,
                       const float* __restrict__ W2, const float* __restrict__ W3,
                       short* __restrict__ Wf, int n4) {
    int i = blockIdx.x * blockDim.x + threadIdx.x;
    if (i < n4) {
        float4 v = ((const float4*)x)[i];
        ushort4 o;
        o.x = (unsigned short)f2bf(v.x);
        o.y = (unsigned short)f2bf(v.y);
        o.z = (unsigned short)f2bf(v.z);
        o.w = (unsigned short)f2bf(v.w);
        ((ushort4*)xbf)[i] = o;
    } else {
        int idx = i - n4;
        if (idx < 4 * 16384) {
            int w = idx >> 14, r = idx & 16383;
            int j = r & 7, lane = (r >> 3) & 63, ct = (r >> 9) & 7, kc = r >> 12;
            int k = kc * 32 + (lane >> 4) * 8 + j;
            int n = ct * 16 + (lane & 15);
            const float* W = (w == 0) ? W0 : (w == 1) ? W1 : (w == 2) ? W2 : W3;
            Wf[idx] = f2bf(W[k * NFEAT + n]);
        }
    }
}

// ---------------- aggregation (bf16), dwordx4 gathers, A-frag-layout output ----------
__global__ __launch_bounds__(256) void k_aggregate_v4(const short* __restrict__ X,
                                                      const int* __restrict__ rowptr,
                                                      const int* __restrict__ adj,
                                                      short* __restrict__ XA, int N) {
    int tid = threadIdx.x;
    int lane = tid & 63;
    int g = lane >> 4;
    int p = lane & 15;
    int wid = (blockIdx.x * blockDim.x + tid) >> 6;
    if (wid >= N) return;
    const uint4* Xv = (const uint4*)X;  // one row = 16 uint4
    float acc[8];
#pragma unroll
    for (int j = 0; j < 8; j++) acc[j] = 0.f;
    int r0 = rowptr[wid], r1 = rowptr[wid + 1];
    for (int e = r0; e < r1; e += 8) {
        int e0 = e + g, e1 = e + 4 + g;
        uint4 v0 = {0u, 0u, 0u, 0u}, v1 = {0u, 0u, 0u, 0u};
        if (e0 < r1) v0 = Xv[(size_t)adj[e0] * 16 + p];
        if (e1 < r1) v1 = Xv[(size_t)adj[e1] * 16 + p];
        acc2(acc[0], acc[1], v0.x);
        acc2(acc[2], acc[3], v0.y);
        acc2(acc[4], acc[5], v0.z);
        acc2(acc[6], acc[7], v0.w);
        acc2(acc[0], acc[1], v1.x);
        acc2(acc[2], acc[3], v1.y);
        acc2(acc[4], acc[5], v1.z);
        acc2(acc[6], acc[7], v1.w);
    }
#pragma unroll
    for (int j = 0; j < 8; j++) {
        acc[j] += __shfl_xor(acc[j], 16);
        acc[j] += __shfl_xor(acc[j], 32);
    }
    if (g == 0) {
        uint4 sv = Xv[(size_t)wid * 16 + p];
        acc2(acc[0], acc[1], sv.x);
        acc2(acc[2], acc[3], sv.y);
        acc2(acc[4], acc[5], sv.z);
        acc2(acc[6], acc[7], sv.w);
        uint4 o;
        o.x = (unsigned)(unsigned short)f2bf(acc[0]) | ((unsigned)(unsigned short)f2bf(acc[1]) << 16);
        o.y = (unsigned)(unsigned short)f2bf(acc[2]) | ((unsigned)(unsigned short)f2bf(acc[3]) << 16);
        o.z = (unsigned)(unsigned short)f2bf(acc[4]) | ((unsigned)(unsigned short)f2bf(acc[5]) << 16);
        o.w = (unsigned)(unsigned short)f2bf(acc[6]) | ((unsigned)(unsigned short)f2bf(acc[7]) << 16);
        size_t dst = ((size_t)(wid >> 4) * 4 + (p >> 2)) * 512 +
                     (size_t)(((p & 3) * 16 + (wid & 15)) * 8);
        *(uint4*)(XA + dst) = o;
    }
}

// ---------------- MFMA GEMM: frag loads; per-ct LDS-transposed dwordx4 C stores ---------
// Epilogue: each wave stages its 32x16 C-tile for one ct in a private 1KB LDS buffer
// (no __syncthreads — wave-order DS), then emits 1 dwordx4 store/lane. 8 wide stores
// replace 64 scalar 2B stores (the R11 epilogue's partial-line write storm).
template <bool BN_RELU_IN, bool RELU_OUT, bool STATS, bool FRAG_OUT>
__global__ __launch_bounds__(256) void k_gemm_mfma(const short* __restrict__ A,
                                                   const short* __restrict__ Wf,
                                                   const float* __restrict__ bias,
                                                   float* __restrict__ stats,
                                                   const float* __restrict__ gamma,
                                                   const float* __restrict__ beta,
                                                   short* __restrict__ C, int N) {
    __shared__ float s_aux[256];       // STATS: sum|sq ; BN: scale|shift
    __shared__ short c_tile[4][512];   // per-wave 32x16 C staging (1KB each)
    int tid = threadIdx.x;
    int wave = tid >> 6, lane = tid & 63;
    int quad = lane >> 4, l16 = lane & 15;
    int row_base = blockIdx.x * 128 + wave * 32;

    if constexpr (STATS) {
        s_aux[tid] = 0.f;
        __syncthreads();
    }
    if constexpr (BN_RELU_IN) {
        if (tid < NFEAT) {
            float mean = stats[tid] / (float)N;
            float var = stats[NFEAT + tid] / (float)N - mean * mean;
            float inv = rsqrtf(var + BN_EPS);
            float sc = gamma[tid] * inv;
            s_aux[tid] = sc;
            s_aux[NFEAT + tid] = beta[tid] - mean * sc;
        }
        __syncthreads();
    }

    f32x4 acc[2][8];
#pragma unroll
    for (int i = 0; i < 2; i++)
#pragma unroll
        for (int j = 0; j < 8; j++) acc[i][j] = (f32x4){0.f, 0.f, 0.f, 0.f};

    const short* af = A + ((size_t)(blockIdx.x * 8 + wave * 2) * 4) * 512;

#pragma unroll
    for (int kc = 0; kc < 4; ++kc) {
        bf16x8 a0 = *(const bf16x8*)(af + (size_t)kc * 512 + lane * 8);
        bf16x8 a1 = *(const bf16x8*)(af + (size_t)(4 + kc) * 512 + lane * 8);
        if constexpr (BN_RELU_IN) {
            int koff = kc * 32 + quad * 8;
#pragma unroll
            for (int j = 0; j < 8; j++) {
                float sc = s_aux[koff + j];
                float sh = s_aux[NFEAT + koff + j];
                a0[j] = f2bf(fmaxf(bf2f(a0[j]) * sc + sh, 0.f));
                a1[j] = f2bf(fmaxf(bf2f(a1[j]) * sc + sh, 0.f));
            }
        }
        const short* wp = Wf + ((size_t)(kc * 8) * 64 + lane) * 8;
#pragma unroll
        for (int ct = 0; ct < 8; ++ct) {
            bf16x8 b = *(const bf16x8*)(wp + (size_t)ct * 64 * 8);
            acc[0][ct] = __builtin_amdgcn_mfma_f32_16x16x32_bf16(a0, b, acc[0][ct], 0, 0, 0);
            acc[1][ct] = __builtin_amdgcn_mfma_f32_16x16x32_bf16(a1, b, acc[1][ct], 0, 0, 0);
        }
    }

    // C/D layout: col = ct*16 + l16, local row = rt*16 + quad*4 + reg
    short* tile = &c_tile[wave][0];
    int row2 = lane >> 1, half = lane & 1;  // store-phase mapping
#pragma unroll
    for (int ct = 0; ct < 8; ++ct) {
        int col = ct * 16 + l16;
        float bv = bias[col];
        float ls = 0.f, ls2 = 0.f;
#pragma unroll
        for (int rt = 0; rt < 2; ++rt) {
#pragma unroll
            for (int reg = 0; reg < 4; ++reg) {
                int lrow = rt * 16 + quad * 4 + reg;
                float v = acc[rt][ct][reg] + bv;
                if constexpr (RELU_OUT) v = fmaxf(v, 0.f);
                if constexpr (STATS) {
                    if (row_base + lrow < N) { ls += v; ls2 += v * v; }
                }
                tile[lrow * 16 + l16] = f2bf(v);
            }
        }
        if constexpr (STATS) {
            atomicAdd(&s_aux[col], ls);
            atomicAdd(&s_aux[NFEAT + col], ls2);
        }
        // wave-private tile: same-wave DS ordering suffices, no barrier
        uint4 val = *(const uint4*)(tile + row2 * 16 + half * 8);
        int grow = row_base + row2;
        if (grow < N) {
            int col0 = ct * 16 + half * 8;
            if constexpr (FRAG_OUT) {
                size_t addr = ((size_t)(grow >> 4) * 4 + (col0 >> 5)) * 512 +
                              (size_t)((((col0 >> 3) & 3) * 16 + (grow & 15)) * 8);
                *(uint4*)(C + addr) = val;
            } else {
                *(uint4*)(C + (size_t)grow * NFEAT + col0) = val;
            }
        }
    }

    if constexpr (STATS) {
        __syncthreads();
        if (tid < NFEAT) {
            atomicAdd(&stats[tid], s_aux[tid]);
            atomicAdd(&stats[NFEAT + tid], s_aux[NFEAT + tid]);
        }
    }
}

// ---------------- node-parallel pooling (batch sorted; per-run register accum) ----------
__global__ __launch_bounds__(256) void k_pool2(const short* __restrict__ H2,
                                               const int* __restrict__ batch,
                                               float* __restrict__ pooled, int N) {
    int t = threadIdx.x;
    int c2 = t & 63;
    int rofs = t >> 6;
    int n0 = blockIdx.x * 128;
    int cur = -1;
    float ax = 0.f, ay = 0.f;
    for (int i = 0; i < 32; ++i) {
        int n = n0 + rofs + i * 4;
        if (n >= N) break;
        int g = batch[n];
        if (g != cur) {
            if (cur >= 0) {
                atomicAdd(&pooled[cur * NFEAT + c2 * 2], ax);
                atomicAdd(&pooled[cur * NFEAT + c2 * 2 + 1], ay);
            }
            cur = g; ax = 0.f; ay = 0.f;
        }
        unsigned v = *(const unsigned*)(H2 + (size_t)n * NFEAT + c2 * 2);
        ax += bf2f((short)(v & 0xffff));
        ay += bf2f((short)(v >> 16));
    }
    if (cur >= 0) {
        atomicAdd(&pooled[cur * NFEAT + c2 * 2], ax);
        atomicAdd(&pooled[cur * NFEAT + c2 * 2 + 1], ay);
    }
}

__global__ void k_final(const float* __restrict__ pooled, const float* __restrict__ Wl,
                        const float* __restrict__ bl, float* __restrict__ out) {
    int idx = blockIdx.x * blockDim.x + threadIdx.x;
    if (idx >= NGRAPHS * TGRAPH) return;
    int g = idx / TGRAPH, t = idx % TGRAPH;
    const float* p = pooled + (size_t)g * NFEAT;
    float acc = bl[t];
#pragma unroll 16
    for (int k = 0; k < NFEAT; ++k) acc += p[k] * Wl[k * TGRAPH + t];
    out[idx] = acc;
}

extern "C" void kernel_launch(void* const* d_in, const int* in_sizes, int n_in,
                              void* d_out, int out_size, void* d_ws, size_t ws_size,
                              hipStream_t stream) {
    const float* x = (const float*)d_in[0];
    const int* ei = (const int*)d_in[1];
    const int* batch = (const int*)d_in[2];
    const float* W1a = (const float*)d_in[3];
    const float* b1a = (const float*)d_in[4];
    const float* g1 = (const float*)d_in[5];
    const float* bt1 = (const float*)d_in[6];
    const float* W1b = (const float*)d_in[7];
    const float* b1b = (const float*)d_in[8];
    const float* W2a = (const float*)d_in[9];
    const float* b2a = (const float*)d_in[10];
    const float* g2 = (const float*)d_in[11];
    const float* bt2 = (const float*)d_in[12];
    const float* W2b = (const float*)d_in[13];
    const float* b2b = (const float*)d_in[14];
    const float* Wl = (const float*)d_in[15];
    const float* bl = (const float*)d_in[16];
    float* out = (float*)d_out;

    int N = in_sizes[2];
    int E = in_sizes[1] / 2;
    int nb = (N + 511) >> 9;
    const int* src = ei;
    const int* dst = ei + E;

    int gemmBlocks = (N + 127) / 128;
    int padRows = gemmBlocks * 128;

    char* ws = (char*)d_ws;
    size_t off = 0;
    auto alloc = [&](size_t bytes) -> void* {
        void* p = ws + off;
        off = (off + bytes + 255) & ~(size_t)255;
        return p;
    };
    short* xbf = (short*)alloc((size_t)N * NFEAT * 2);        // row-major (gather input)
    short* ag = (short*)alloc((size_t)padRows * NFEAT * 2);   // frag layout
    short* ybf = (short*)alloc((size_t)padRows * NFEAT * 2);  // frag layout
    short* hbf = (short*)alloc((size_t)N * NFEAT * 2);        // row-major (gather input)
    short* h2bf = (short*)alloc((size_t)N * NFEAT * 2);       // row-major (pool input)
    short* Wf = (short*)alloc((size_t)4 * 16384 * 2);
    int* adj = (int*)alloc((size_t)E * 4);
    int2* binned = (int2*)alloc((size_t)E * 8);
    int* rowptr = (int*)alloc((size_t)(N + 1) * 4);
    int* bbase = (int*)alloc(257 * 4);
    int* cur256 = (int*)alloc(256 * 4);
    // zero-region: bhist + stats1 + stats2 + pooled
    int* bhist = (int*)alloc(256 * 4);
    float* stats1 = (float*)alloc(256 * 4);
    float* stats2 = (float*)alloc(256 * 4);
    float* pooled = (float*)alloc((size_t)NGRAPHS * NFEAT * 4);
    size_t zbytes = (char*)(pooled + (size_t)NGRAPHS * NFEAT) - (char*)bhist;

    hipMemsetAsync(bhist, 0, zbytes, stream);

    // ---- CSR build (bucket-local) ----
    k_bucket_hist<<<784, 256, 0, stream>>>(dst, bhist, E);
    k_bucket_scan<<<1, 256, 0, stream>>>(bhist, bbase, cur256, E);
    k_bin_scatter<<<(E + BIN_CHUNK - 1) / BIN_CHUNK, 256, 0, stream>>>(src, dst, cur256, binned, E);
    k_bucket_csr<<<nb, 512, 0, stream>>>(binned, bbase, rowptr, adj, N, E, nb);

    // ---- dtype prep (fused) ----
    int n4 = N * NFEAT / 4;
    int prepTot = n4 + 4 * 16384;
    k_prep<<<(prepTot + 255) / 256, 256, 0, stream>>>(x, xbf, W1a, W1b, W2a, W2b, Wf, n4);

    int aggBlocks = (N + 3) / 4;  // one wave per node

    // ---- layer 1 ----
    k_aggregate_v4<<<aggBlocks, 256, 0, stream>>>(xbf, rowptr, adj, ag, N);
    k_gemm_mfma<false, false, true, true><<<gemmBlocks, 256, 0, stream>>>(
        ag, Wf + 0 * 16384, b1a, stats1, nullptr, nullptr, ybf, N);
    k_gemm_mfma<true, true, false, false><<<gemmBlocks, 256, 0, stream>>>(
        ybf, Wf + 1 * 16384, b1b, stats1, g1, bt1, hbf, N);

    // ---- layer 2 ----
    k_aggregate_v4<<<aggBlocks, 256, 0, stream>>>(hbf, rowptr, adj, ag, N);
    k_gemm_mfma<false, false, true, true><<<gemmBlocks, 256, 0, stream>>>(
        ag, Wf + 2 * 16384, b2a, stats2, nullptr, nullptr, ybf, N);
    k_gemm_mfma<true, true, false, false><<<gemmBlocks, 256, 0, stream>>>(
        ybf, Wf + 3 * 16384, b2b, stats2, g2, bt2, h2bf, N);

    // ---- pooling + classifier ----
    k_pool2<<<(N + 127) / 128, 256, 0, stream>>>(h2bf, batch, pooled, N);
    k_final<<<(NGRAPHS * TGRAPH + 255) / 256, 256, 0, stream>>>(pooled, Wl, bl, out);
}

// Round 14
// 457.770 us; speedup vs baseline: 1.1450x; 1.0708x over previous
//
#include <hip/hip_runtime.h>
#include <cstdint>
#include <cstddef>

#define NFEAT 128
#define TGRAPH 10
#define NGRAPHS 512
#define BN_EPS 1e-5f
#define BIN_CHUNK 2048
#define GSPAN 8  // max graphs a 128-row block can span (min graph ~140 rows -> <=3 actual)

typedef __attribute__((ext_vector_type(8))) short bf16x8;
typedef __attribute__((ext_vector_type(4))) float f32x4;

__device__ __forceinline__ float bf2f(short s) {
    union { unsigned u; float f; } c;
    c.u = ((unsigned)(unsigned short)s) << 16;
    return c.f;
}
__device__ __forceinline__ short f2bf(float f) {
    union { float f; unsigned u; } c;
    c.f = f;
    unsigned u = c.u;
    return (short)((u + 0x7fffu + ((u >> 16) & 1u)) >> 16);
}
__device__ __forceinline__ void acc2(float& a, float& b, unsigned v) {
    union { unsigned u; float f; } lo, hi;
    lo.u = v << 16;
    hi.u = v & 0xffff0000u;
    a += lo.f;
    b += hi.f;
}

// A-frag memory layout (shorts): buffer of 16-row tiles; element (row, k) lives at
//   ((row>>4)*4 + (k>>5))*512 + (((k>>3)&3)*16 + (row&15))*8 + (k&7)

// ---------------- CSR build, bucket-local (bucket = dst>>9, <=256 buckets) ----------------
__global__ __launch_bounds__(256) void k_bucket_hist(const int* __restrict__ dst,
                                                     int* __restrict__ bhist, int E) {
    __shared__ int h[256];
    int t = threadIdx.x;
    h[t] = 0;
    __syncthreads();
    for (int e = blockIdx.x * blockDim.x + t; e < E; e += gridDim.x * blockDim.x)
        atomicAdd(&h[dst[e] >> 9], 1);
    __syncthreads();
    if (h[t]) atomicAdd(&bhist[t], h[t]);
}

__global__ void k_bucket_scan(const int* __restrict__ bhist, int* __restrict__ bbase,
                              int* __restrict__ cur256, int E) {
    __shared__ int s[256];
    int t = threadIdx.x;
    int v = bhist[t];
    s[t] = v;
    __syncthreads();
    for (int off = 1; off < 256; off <<= 1) {
        int x = 0;
        if (t >= off) x = s[t - off];
        __syncthreads();
        if (t >= off) s[t] += x;
        __syncthreads();
    }
    int excl = s[t] - v;
    bbase[t] = excl;
    cur256[t] = excl;
    if (t == 255) bbase[256] = E;
}

__global__ __launch_bounds__(256) void k_bin_scatter(const int* __restrict__ src,
                                                     const int* __restrict__ dst,
                                                     int* __restrict__ cur256,
                                                     int2* __restrict__ binned, int E) {
    __shared__ int hist[256];
    __shared__ int base[256];
    int t = threadIdx.x;
    int e0 = blockIdx.x * BIN_CHUNK;
    int e1 = min(e0 + BIN_CHUNK, E);
    hist[t] = 0;
    __syncthreads();
    for (int e = e0 + t; e < e1; e += 256) {
        int b = dst[e] >> 9;
        atomicAdd(&hist[b], 1);
    }
    __syncthreads();
    int c = hist[t];
    if (c > 0) base[t] = atomicAdd(&cur256[t], c);
    __syncthreads();
    hist[t] = 0;
    __syncthreads();
    for (int e = e0 + t; e < e1; e += 256) {
        int d = dst[e];
        int b = d >> 9;
        int loc = atomicAdd(&hist[b], 1);
        binned[base[b] + loc] = make_int2(src[e], d);
    }
}

__global__ __launch_bounds__(512) void k_bucket_csr(const int2* __restrict__ binned,
                                                    const int* __restrict__ bbase,
                                                    int* __restrict__ rowptr,
                                                    int* __restrict__ adj,
                                                    int N, int E, int nb) {
    __shared__ int deg[512];
    __shared__ int cur[512];
    int b = blockIdx.x;
    int t = threadIdx.x;
    int e0 = bbase[b], e1 = bbase[b + 1];
    deg[t] = 0;
    __syncthreads();
    for (int e = e0 + t; e < e1; e += 512)
        atomicAdd(&deg[binned[e].y & 511], 1);
    __syncthreads();
    int v = deg[t];
    for (int off = 1; off < 512; off <<= 1) {
        int x = 0;
        if (t >= off) x = deg[t - off];
        __syncthreads();
        if (t >= off) deg[t] += x;
        __syncthreads();
    }
    int excl = deg[t] - v;
    cur[t] = excl;
    int node = b * 512 + t;
    if (node < N) rowptr[node] = e0 + excl;
    if (b == nb - 1 && t == 0) rowptr[N] = E;
    __syncthreads();
    for (int e = e0 + t; e < e1; e += 512) {
        int2 p = binned[e];
        int loc = atomicAdd(&cur[p.y & 511], 1);
        adj[e0 + loc] = p.x;
    }
}

// ---------------- fused fp32->bf16 convert (x) + weight frag prep ----------------
__global__ void k_prep(const float* __restrict__ x, short* __restrict__ xbf,
                       const float* __restrict__ W0, const float* __restrict__ W1,
                       const float* __restrict__ W2, const float* __restrict__ W3,
                       short* __restrict__ Wf, int n4) {
    int i = blockIdx.x * blockDim.x + threadIdx.x;
    if (i < n4) {
        float4 v = ((const float4*)x)[i];
        ushort4 o;
        o.x = (unsigned short)f2bf(v.x);
        o.y = (unsigned short)f2bf(v.y);
        o.z = (unsigned short)f2bf(v.z);
        o.w = (unsigned short)f2bf(v.w);
        ((ushort4*)xbf)[i] = o;
    } else {
        int idx = i - n4;
        if (idx < 4 * 16384) {
            int w = idx >> 14, r = idx & 16383;
            int j = r & 7, lane = (r >> 3) & 63, ct = (r >> 9) & 7, kc = r >> 12;
            int k = kc * 32 + (lane >> 4) * 8 + j;
            int n = ct * 16 + (lane & 15);
            const float* W = (w == 0) ? W0 : (w == 1) ? W1 : (w == 2) ? W2 : W3;
            Wf[idx] = f2bf(W[k * NFEAT + n]);
        }
    }
}

// ---------------- aggregation (bf16), dwordx4 gathers x4-deep, A-frag-layout output ------
// wave = 1 node. group g=lane>>4 -> edge slot, chunk p=lane&15 -> 16B of 256B row.
// 16 edges (4 dwordx4 loads/lane) in flight per iteration for latency hiding.
__global__ __launch_bounds__(256) void k_aggregate_v4(const short* __restrict__ X,
                                                      const int* __restrict__ rowptr,
                                                      const int* __restrict__ adj,
                                                      short* __restrict__ XA, int N) {
    int tid = threadIdx.x;
    int lane = tid & 63;
    int g = lane >> 4;
    int p = lane & 15;
    int wid = (blockIdx.x * blockDim.x + tid) >> 6;
    if (wid >= N) return;
    const uint4* Xv = (const uint4*)X;  // one row = 16 uint4
    float acc[8];
#pragma unroll
    for (int j = 0; j < 8; j++) acc[j] = 0.f;
    int r0 = rowptr[wid], r1 = rowptr[wid + 1];
    for (int e = r0; e < r1; e += 16) {
        int ea = e + g, eb = e + 4 + g, ec = e + 8 + g, ed = e + 12 + g;
        uint4 v0 = {0u, 0u, 0u, 0u}, v1 = {0u, 0u, 0u, 0u};
        uint4 v2 = {0u, 0u, 0u, 0u}, v3 = {0u, 0u, 0u, 0u};
        if (ea < r1) v0 = Xv[(size_t)adj[ea] * 16 + p];
        if (eb < r1) v1 = Xv[(size_t)adj[eb] * 16 + p];
        if (ec < r1) v2 = Xv[(size_t)adj[ec] * 16 + p];
        if (ed < r1) v3 = Xv[(size_t)adj[ed] * 16 + p];
        acc2(acc[0], acc[1], v0.x); acc2(acc[2], acc[3], v0.y);
        acc2(acc[4], acc[5], v0.z); acc2(acc[6], acc[7], v0.w);
        acc2(acc[0], acc[1], v1.x); acc2(acc[2], acc[3], v1.y);
        acc2(acc[4], acc[5], v1.z); acc2(acc[6], acc[7], v1.w);
        acc2(acc[0], acc[1], v2.x); acc2(acc[2], acc[3], v2.y);
        acc2(acc[4], acc[5], v2.z); acc2(acc[6], acc[7], v2.w);
        acc2(acc[0], acc[1], v3.x); acc2(acc[2], acc[3], v3.y);
        acc2(acc[4], acc[5], v3.z); acc2(acc[6], acc[7], v3.w);
    }
#pragma unroll
    for (int j = 0; j < 8; j++) {
        acc[j] += __shfl_xor(acc[j], 16);
        acc[j] += __shfl_xor(acc[j], 32);
    }
    if (g == 0) {
        uint4 sv = Xv[(size_t)wid * 16 + p];
        acc2(acc[0], acc[1], sv.x); acc2(acc[2], acc[3], sv.y);
        acc2(acc[4], acc[5], sv.z); acc2(acc[6], acc[7], sv.w);
        uint4 o;
        o.x = (unsigned)(unsigned short)f2bf(acc[0]) | ((unsigned)(unsigned short)f2bf(acc[1]) << 16);
        o.y = (unsigned)(unsigned short)f2bf(acc[2]) | ((unsigned)(unsigned short)f2bf(acc[3]) << 16);
        o.z = (unsigned)(unsigned short)f2bf(acc[4]) | ((unsigned)(unsigned short)f2bf(acc[5]) << 16);
        o.w = (unsigned)(unsigned short)f2bf(acc[6]) | ((unsigned)(unsigned short)f2bf(acc[7]) << 16);
        size_t dst = ((size_t)(wid >> 4) * 4 + (p >> 2)) * 512 +
                     (size_t)(((p & 3) * 16 + (wid & 15)) * 8);
        *(uint4*)(XA + dst) = o;
    }
}

// ---------------- MFMA GEMM: frag loads; LDS-transposed wide C stores; opt. fused pool ---
template <bool BN_RELU_IN, bool RELU_OUT, bool STATS, bool FRAG_OUT, bool POOL>
__global__ __launch_bounds__(256) void k_gemm_mfma(const short* __restrict__ A,
                                                   const short* __restrict__ Wf,
                                                   const float* __restrict__ bias,
                                                   float* __restrict__ stats,
                                                   const float* __restrict__ gamma,
                                                   const float* __restrict__ beta,
                                                   const int* __restrict__ batch,
                                                   float* __restrict__ pooled,
                                                   short* __restrict__ C, int N) {
    __shared__ float s_aux[256];       // STATS: sum|sq ; BN: scale|shift
    __shared__ short c_tile[4][512];   // per-wave 32x16 C staging
    __shared__ float s_pool[GSPAN][NFEAT];
    int tid = threadIdx.x;
    int wave = tid >> 6, lane = tid & 63;
    int quad = lane >> 4, l16 = lane & 15;
    int row_base = blockIdx.x * 128 + wave * 32;

    int gbase = 0;
    if constexpr (POOL) {
        int first = blockIdx.x * 128;
        gbase = (first < N) ? batch[first] : 0;
        for (int i = tid; i < GSPAN * NFEAT; i += 256) s_pool[i >> 7][i & 127] = 0.f;
    }
    if constexpr (STATS) s_aux[tid] = 0.f;
    if constexpr (BN_RELU_IN) {
        if (tid < NFEAT) {
            float mean = stats[tid] / (float)N;
            float var = stats[NFEAT + tid] / (float)N - mean * mean;
            float inv = rsqrtf(var + BN_EPS);
            float sc = gamma[tid] * inv;
            s_aux[tid] = sc;
            s_aux[NFEAT + tid] = beta[tid] - mean * sc;
        }
    }
    if constexpr (STATS || BN_RELU_IN || POOL) __syncthreads();

    f32x4 acc[2][8];
#pragma unroll
    for (int i = 0; i < 2; i++)
#pragma unroll
        for (int j = 0; j < 8; j++) acc[i][j] = (f32x4){0.f, 0.f, 0.f, 0.f};

    const short* af = A + ((size_t)(blockIdx.x * 8 + wave * 2) * 4) * 512;

#pragma unroll
    for (int kc = 0; kc < 4; ++kc) {
        bf16x8 a0 = *(const bf16x8*)(af + (size_t)kc * 512 + lane * 8);
        bf16x8 a1 = *(const bf16x8*)(af + (size_t)(4 + kc) * 512 + lane * 8);
        if constexpr (BN_RELU_IN) {
            int koff = kc * 32 + quad * 8;
#pragma unroll
            for (int j = 0; j < 8; j++) {
                float sc = s_aux[koff + j];
                float sh = s_aux[NFEAT + koff + j];
                a0[j] = f2bf(fmaxf(bf2f(a0[j]) * sc + sh, 0.f));
                a1[j] = f2bf(fmaxf(bf2f(a1[j]) * sc + sh, 0.f));
            }
        }
        const short* wp = Wf + ((size_t)(kc * 8) * 64 + lane) * 8;
#pragma unroll
        for (int ct = 0; ct < 8; ++ct) {
            bf16x8 b = *(const bf16x8*)(wp + (size_t)ct * 64 * 8);
            acc[0][ct] = __builtin_amdgcn_mfma_f32_16x16x32_bf16(a0, b, acc[0][ct], 0, 0, 0);
            acc[1][ct] = __builtin_amdgcn_mfma_f32_16x16x32_bf16(a1, b, acc[1][ct], 0, 0, 0);
        }
    }

    // graph index per (rt,reg) row, hoisted (POOL only)
    int dg[8];
    if constexpr (POOL) {
#pragma unroll
        for (int rt = 0; rt < 2; ++rt)
#pragma unroll
            for (int reg = 0; reg < 4; ++reg) {
                int row = row_base + rt * 16 + quad * 4 + reg;
                dg[rt * 4 + reg] = (row < N) ? (batch[row] - gbase) : -1;
            }
    }

    // C/D layout: col = ct*16 + l16, local row = rt*16 + quad*4 + reg
    short* tile = &c_tile[wave][0];
    int row2 = lane >> 1, half = lane & 1;
#pragma unroll
    for (int ct = 0; ct < 8; ++ct) {
        int col = ct * 16 + l16;
        float bv = bias[col];
        float ls = 0.f, ls2 = 0.f;
        int cg = -1;
        float ps = 0.f;
#pragma unroll
        for (int rt = 0; rt < 2; ++rt) {
#pragma unroll
            for (int reg = 0; reg < 4; ++reg) {
                int lrow = rt * 16 + quad * 4 + reg;
                float v = acc[rt][ct][reg] + bv;
                if constexpr (RELU_OUT) v = fmaxf(v, 0.f);
                if constexpr (STATS) {
                    if (row_base + lrow < N) { ls += v; ls2 += v * v; }
                }
                if constexpr (POOL) {
                    int d = dg[rt * 4 + reg];
                    if (d != cg) {
                        if (cg >= 0) atomicAdd(&s_pool[cg & (GSPAN - 1)][col], ps);
                        cg = d; ps = 0.f;
                    }
                    if (d >= 0) ps += v;
                } else {
                    tile[lrow * 16 + l16] = f2bf(v);
                }
            }
        }
        if constexpr (POOL) {
            if (cg >= 0) atomicAdd(&s_pool[cg & (GSPAN - 1)][col], ps);
        }
        if constexpr (STATS) {
            // cross-quad reduce, then one atomic per column per wave
            ls += __shfl_xor(ls, 16);
            ls += __shfl_xor(ls, 32);
            ls2 += __shfl_xor(ls2, 16);
            ls2 += __shfl_xor(ls2, 32);
            if (quad == 0) {
                atomicAdd(&s_aux[col], ls);
                atomicAdd(&s_aux[NFEAT + col], ls2);
            }
        }
        if constexpr (!POOL) {
            // wave-private tile: same-wave DS ordering suffices, no barrier
            uint4 val = *(const uint4*)(tile + row2 * 16 + half * 8);
            int grow = row_base + row2;
            if (grow < N) {
                int col0 = ct * 16 + half * 8;
                if constexpr (FRAG_OUT) {
                    size_t addr = ((size_t)(grow >> 4) * 4 + (col0 >> 5)) * 512 +
                                  (size_t)((((col0 >> 3) & 3) * 16 + (grow & 15)) * 8);
                    *(uint4*)(C + addr) = val;
                } else {
                    *(uint4*)(C + (size_t)grow * NFEAT + col0) = val;
                }
            }
        }
    }

    if constexpr (STATS) {
        __syncthreads();
        if (tid < NFEAT) {
            atomicAdd(&stats[tid], s_aux[tid]);
            atomicAdd(&stats[NFEAT + tid], s_aux[NFEAT + tid]);
        }
    }
    if constexpr (POOL) {
        __syncthreads();
        for (int i = tid; i < GSPAN * NFEAT; i += 256) {
            float v = s_pool[i >> 7][i & 127];
            if (v != 0.f) {
                int gg = gbase + (i >> 7);
                if (gg < NGRAPHS) atomicAdd(&pooled[gg * NFEAT + (i & 127)], v);
            }
        }
    }
}

__global__ void k_final(const float* __restrict__ pooled, const float* __restrict__ Wl,
                        const float* __restrict__ bl, float* __restrict__ out) {
    int idx = blockIdx.x * blockDim.x + threadIdx.x;
    if (idx >= NGRAPHS * TGRAPH) return;
    int g = idx / TGRAPH, t = idx % TGRAPH;
    const float* p = pooled + (size_t)g * NFEAT;
    float acc = bl[t];
#pragma unroll 16
    for (int k = 0; k < NFEAT; ++k) acc += p[k] * Wl[k * TGRAPH + t];
    out[idx] = acc;
}

extern "C" void kernel_launch(void* const* d_in, const int* in_sizes, int n_in,
                              void* d_out, int out_size, void* d_ws, size_t ws_size,
                              hipStream_t stream) {
    const float* x = (const float*)d_in[0];
    const int* ei = (const int*)d_in[1];
    const int* batch = (const int*)d_in[2];
    const float* W1a = (const float*)d_in[3];
    const float* b1a = (const float*)d_in[4];
    const float* g1 = (const float*)d_in[5];
    const float* bt1 = (const float*)d_in[6];
    const float* W1b = (const float*)d_in[7];
    const float* b1b = (const float*)d_in[8];
    const float* W2a = (const float*)d_in[9];
    const float* b2a = (const float*)d_in[10];
    const float* g2 = (const float*)d_in[11];
    const float* bt2 = (const float*)d_in[12];
    const float* W2b = (const float*)d_in[13];
    const float* b2b = (const float*)d_in[14];
    const float* Wl = (const float*)d_in[15];
    const float* bl = (const float*)d_in[16];
    float* out = (float*)d_out;

    int N = in_sizes[2];
    int E = in_sizes[1] / 2;
    int nb = (N + 511) >> 9;
    const int* src = ei;
    const int* dst = ei + E;

    int gemmBlocks = (N + 127) / 128;
    int padRows = gemmBlocks * 128;

    char* ws = (char*)d_ws;
    size_t off = 0;
    auto alloc = [&](size_t bytes) -> void* {
        void* p = ws + off;
        off = (off + bytes + 255) & ~(size_t)255;
        return p;
    };
    short* xbf = (short*)alloc((size_t)N * NFEAT * 2);        // row-major (gather input)
    short* ag = (short*)alloc((size_t)padRows * NFEAT * 2);   // frag layout
    short* ybf = (short*)alloc((size_t)padRows * NFEAT * 2);  // frag layout
    short* hbf = (short*)alloc((size_t)N * NFEAT * 2);        // row-major (gather input)
    short* Wf = (short*)alloc((size_t)4 * 16384 * 2);
    int* adj = (int*)alloc((size_t)E * 4);
    int2* binned = (int2*)alloc((size_t)E * 8);
    int* rowptr = (int*)alloc((size_t)(N + 1) * 4);
    int* bbase = (int*)alloc(257 * 4);
    int* cur256 = (int*)alloc(256 * 4);
    // zero-region: bhist + stats1 + stats2 + pooled
    int* bhist = (int*)alloc(256 * 4);
    float* stats1 = (float*)alloc(256 * 4);
    float* stats2 = (float*)alloc(256 * 4);
    float* pooled = (float*)alloc((size_t)NGRAPHS * NFEAT * 4);
    size_t zbytes = (char*)(pooled + (size_t)NGRAPHS * NFEAT) - (char*)bhist;

    hipMemsetAsync(bhist, 0, zbytes, stream);

    // ---- CSR build (bucket-local) ----
    k_bucket_hist<<<784, 256, 0, stream>>>(dst, bhist, E);
    k_bucket_scan<<<1, 256, 0, stream>>>(bhist, bbase, cur256, E);
    k_bin_scatter<<<(E + BIN_CHUNK - 1) / BIN_CHUNK, 256, 0, stream>>>(src, dst, cur256, binned, E);
    k_bucket_csr<<<nb, 512, 0, stream>>>(binned, bbase, rowptr, adj, N, E, nb);

    // ---- dtype prep (fused) ----
    int n4 = N * NFEAT / 4;
    int prepTot = n4 + 4 * 16384;
    k_prep<<<(prepTot + 255) / 256, 256, 0, stream>>>(x, xbf, W1a, W1b, W2a, W2b, Wf, n4);

    int aggBlocks = (N + 3) / 4;  // one wave per node

    // ---- layer 1 ----
    k_aggregate_v4<<<aggBlocks, 256, 0, stream>>>(xbf, rowptr, adj, ag, N);
    k_gemm_mfma<false, false, true, true, false><<<gemmBlocks, 256, 0, stream>>>(
        ag, Wf + 0 * 16384, b1a, stats1, nullptr, nullptr, nullptr, nullptr, ybf, N);
    k_gemm_mfma<true, true, false, false, false><<<gemmBlocks, 256, 0, stream>>>(
        ybf, Wf + 1 * 16384, b1b, stats1, g1, bt1, nullptr, nullptr, hbf, N);

    // ---- layer 2 (GEMM-b pools directly; no h2bf materialization) ----
    k_aggregate_v4<<<aggBlocks, 256, 0, stream>>>(hbf, rowptr, adj, ag, N);
    k_gemm_mfma<false, false, true, true, false><<<gemmBlocks, 256, 0, stream>>>(
        ag, Wf + 2 * 16384, b2a, stats2, nullptr, nullptr, nullptr, nullptr, ybf, N);
    k_gemm_mfma<true, true, false, false, true><<<gemmBlocks, 256, 0, stream>>>(
        ybf, Wf + 3 * 16384, b2b, stats2, g2, bt2, batch, pooled, nullptr, N);

    // ---- classifier ----
    k_final<<<(NGRAPHS * TGRAPH + 255) / 256, 256, 0, stream>>>(pooled, Wl, bl, out);
}

// Round 15
// 438.417 us; speedup vs baseline: 1.1955x; 1.0441x over previous
//
#include <hip/hip_runtime.h>
#include <cstdint>
#include <cstddef>

#define NFEAT 128
#define TGRAPH 10
#define NGRAPHS 512
#define BN_EPS 1e-5f
#define BIN_CHUNK 2048
#define GSPAN 8    // max graphs a 128-row block can span
#define TSTR 24    // c_tile row stride in shorts: 48B rows, 16B-aligned, 2-way banks (free)

typedef __attribute__((ext_vector_type(8))) short bf16x8;
typedef __attribute__((ext_vector_type(4))) float f32x4;
typedef __attribute__((ext_vector_type(2))) float f32x2;

__device__ __forceinline__ float bf2f(short s) {
    union { unsigned u; float f; } c;
    c.u = ((unsigned)(unsigned short)s) << 16;
    return c.f;
}
__device__ __forceinline__ short f2bf(float f) {
    union { float f; unsigned u; } c;
    c.f = f;
    unsigned u = c.u;
    return (short)((u + 0x7fffu + ((u >> 16) & 1u)) >> 16);
}
// packed accumulate: both bf16 halves of dword v into a[0] (low) and a[1] (high)
// ext_vector add -> v_pk_add_f32 (1 inst for 2 adds): 3 VALU/dword vs 4 scalar
__device__ __forceinline__ void accp(f32x2& a, unsigned v) {
    union { unsigned u; float f; } lo, hi;
    lo.u = v << 16;
    hi.u = v & 0xffff0000u;
    f32x2 t;
    t[0] = lo.f;
    t[1] = hi.f;
    a += t;
}

// A-frag memory layout (shorts): buffer of 16-row tiles; element (row, k) lives at
//   ((row>>4)*4 + (k>>5))*512 + (((k>>3)&3)*16 + (row&15))*8 + (k&7)

// ---------------- CSR build, bucket-local (bucket = dst>>9, <=256 buckets) ----------------
__global__ void k_bucket_scan(const int* __restrict__ bhist, int* __restrict__ bbase,
                              int* __restrict__ cur256, int E) {
    __shared__ int s[256];
    int t = threadIdx.x;
    int v = bhist[t];
    s[t] = v;
    __syncthreads();
    for (int off = 1; off < 256; off <<= 1) {
        int x = 0;
        if (t >= off) x = s[t - off];
        __syncthreads();
        if (t >= off) s[t] += x;
        __syncthreads();
    }
    int excl = s[t] - v;
    bbase[t] = excl;
    cur256[t] = excl;
    if (t == 255) bbase[256] = E;
}

__global__ __launch_bounds__(256) void k_bin_scatter(const int* __restrict__ src,
                                                     const int* __restrict__ dst,
                                                     int* __restrict__ cur256,
                                                     int2* __restrict__ binned, int E) {
    __shared__ int hist[256];
    __shared__ int base[256];
    int t = threadIdx.x;
    int e0 = blockIdx.x * BIN_CHUNK;
    int e1 = min(e0 + BIN_CHUNK, E);
    hist[t] = 0;
    __syncthreads();
    for (int e = e0 + t; e < e1; e += 256) {
        int b = dst[e] >> 9;
        atomicAdd(&hist[b], 1);
    }
    __syncthreads();
    int c = hist[t];
    if (c > 0) base[t] = atomicAdd(&cur256[t], c);
    __syncthreads();
    hist[t] = 0;
    __syncthreads();
    for (int e = e0 + t; e < e1; e += 256) {
        int d = dst[e];
        int b = d >> 9;
        int loc = atomicAdd(&hist[b], 1);
        binned[base[b] + loc] = make_int2(src[e], d);
    }
}

__global__ __launch_bounds__(512) void k_bucket_csr(const int2* __restrict__ binned,
                                                    const int* __restrict__ bbase,
                                                    int* __restrict__ rowptr,
                                                    int* __restrict__ adj,
                                                    int N, int E, int nb) {
    __shared__ int deg[512];
    __shared__ int cur[512];
    int b = blockIdx.x;
    int t = threadIdx.x;
    int e0 = bbase[b], e1 = bbase[b + 1];
    deg[t] = 0;
    __syncthreads();
    for (int e = e0 + t; e < e1; e += 512)
        atomicAdd(&deg[binned[e].y & 511], 1);
    __syncthreads();
    int v = deg[t];
    for (int off = 1; off < 512; off <<= 1) {
        int x = 0;
        if (t >= off) x = deg[t - off];
        __syncthreads();
        if (t >= off) deg[t] += x;
        __syncthreads();
    }
    int excl = deg[t] - v;
    cur[t] = excl;
    int node = b * 512 + t;
    if (node < N) rowptr[node] = e0 + excl;
    if (b == nb - 1 && t == 0) rowptr[N] = E;
    __syncthreads();
    for (int e = e0 + t; e < e1; e += 512) {
        int2 p = binned[e];
        int loc = atomicAdd(&cur[p.y & 511], 1);
        adj[e0 + loc] = p.x;
    }
}

// ---------------- merged: bucket histogram + fp32->bf16 convert + weight frag prep -------
// blocks [0, hb): edge-bucket histogram; blocks [hb, ...): convert/prep (independent work,
// one dispatch instead of two)
__global__ __launch_bounds__(256) void k_prep_hist(const int* __restrict__ dst,
                                                   int* __restrict__ bhist, int E, int hb,
                                                   const float* __restrict__ x,
                                                   short* __restrict__ xbf,
                                                   const float* __restrict__ W0,
                                                   const float* __restrict__ W1,
                                                   const float* __restrict__ W2,
                                                   const float* __restrict__ W3,
                                                   short* __restrict__ Wf, int n4) {
    int t = threadIdx.x;
    if (blockIdx.x < hb) {
        __shared__ int h[256];
        h[t] = 0;
        __syncthreads();
        for (int e = blockIdx.x * 256 + t; e < E; e += hb * 256)
            atomicAdd(&h[dst[e] >> 9], 1);
        __syncthreads();
        if (h[t]) atomicAdd(&bhist[t], h[t]);
        return;
    }
    int i = (blockIdx.x - hb) * 256 + t;
    if (i < n4) {
        float4 v = ((const float4*)x)[i];
        ushort4 o;
        o.x = (unsigned short)f2bf(v.x);
        o.y = (unsigned short)f2bf(v.y);
        o.z = (unsigned short)f2bf(v.z);
        o.w = (unsigned short)f2bf(v.w);
        ((ushort4*)xbf)[i] = o;
    } else {
        int idx = i - n4;
        if (idx < 4 * 16384) {
            int w = idx >> 14, r = idx & 16383;
            int j = r & 7, lane = (r >> 3) & 63, ct = (r >> 9) & 7, kc = r >> 12;
            int k = kc * 32 + (lane >> 4) * 8 + j;
            int n = ct * 16 + (lane & 15);
            const float* W = (w == 0) ? W0 : (w == 1) ? W1 : (w == 2) ? W2 : W3;
            Wf[idx] = f2bf(W[k * NFEAT + n]);
        }
    }
}

// ---------------- aggregation (bf16), dwordx4 gathers x4-deep, pk_add accumulate --------
__global__ __launch_bounds__(256) void k_aggregate_v4(const short* __restrict__ X,
                                                      const int* __restrict__ rowptr,
                                                      const int* __restrict__ adj,
                                                      short* __restrict__ XA, int N) {
    int tid = threadIdx.x;
    int lane = tid & 63;
    int g = lane >> 4;
    int p = lane & 15;
    int wid = (blockIdx.x * blockDim.x + tid) >> 6;
    if (wid >= N) return;
    const uint4* Xv = (const uint4*)X;  // one row = 16 uint4
    f32x2 ac[4];
#pragma unroll
    for (int j = 0; j < 4; j++) ac[j] = (f32x2){0.f, 0.f};
    int r0 = rowptr[wid], r1 = rowptr[wid + 1];
    for (int e = r0; e < r1; e += 16) {
        int ea = e + g, eb = e + 4 + g, ec = e + 8 + g, ed = e + 12 + g;
        uint4 v0 = {0u, 0u, 0u, 0u}, v1 = {0u, 0u, 0u, 0u};
        uint4 v2 = {0u, 0u, 0u, 0u}, v3 = {0u, 0u, 0u, 0u};
        if (ea < r1) v0 = Xv[(size_t)adj[ea] * 16 + p];
        if (eb < r1) v1 = Xv[(size_t)adj[eb] * 16 + p];
        if (ec < r1) v2 = Xv[(size_t)adj[ec] * 16 + p];
        if (ed < r1) v3 = Xv[(size_t)adj[ed] * 16 + p];
        accp(ac[0], v0.x); accp(ac[1], v0.y); accp(ac[2], v0.z); accp(ac[3], v0.w);
        accp(ac[0], v1.x); accp(ac[1], v1.y); accp(ac[2], v1.z); accp(ac[3], v1.w);
        accp(ac[0], v2.x); accp(ac[1], v2.y); accp(ac[2], v2.z); accp(ac[3], v2.w);
        accp(ac[0], v3.x); accp(ac[1], v3.y); accp(ac[2], v3.z); accp(ac[3], v3.w);
    }
#pragma unroll
    for (int j = 0; j < 4; j++) {
        ac[j][0] += __shfl_xor(ac[j][0], 16);
        ac[j][1] += __shfl_xor(ac[j][1], 16);
        ac[j][0] += __shfl_xor(ac[j][0], 32);
        ac[j][1] += __shfl_xor(ac[j][1], 32);
    }
    if (g == 0) {
        uint4 sv = Xv[(size_t)wid * 16 + p];
        accp(ac[0], sv.x); accp(ac[1], sv.y); accp(ac[2], sv.z); accp(ac[3], sv.w);
        uint4 o;
        o.x = (unsigned)(unsigned short)f2bf(ac[0][0]) | ((unsigned)(unsigned short)f2bf(ac[0][1]) << 16);
        o.y = (unsigned)(unsigned short)f2bf(ac[1][0]) | ((unsigned)(unsigned short)f2bf(ac[1][1]) << 16);
        o.z = (unsigned)(unsigned short)f2bf(ac[2][0]) | ((unsigned)(unsigned short)f2bf(ac[2][1]) << 16);
        o.w = (unsigned)(unsigned short)f2bf(ac[3][0]) | ((unsigned)(unsigned short)f2bf(ac[3][1]) << 16);
        size_t dst = ((size_t)(wid >> 4) * 4 + (p >> 2)) * 512 +
                     (size_t)(((p & 3) * 16 + (wid & 15)) * 8);
        *(uint4*)(XA + dst) = o;
    }
}

// ---------------- MFMA GEMM: frag loads; LDS-transposed wide C stores; opt. fused pool ---
template <bool BN_RELU_IN, bool RELU_OUT, bool STATS, bool FRAG_OUT, bool POOL>
__global__ __launch_bounds__(256) void k_gemm_mfma(const short* __restrict__ A,
                                                   const short* __restrict__ Wf,
                                                   const float* __restrict__ bias,
                                                   float* __restrict__ stats,
                                                   const float* __restrict__ gamma,
                                                   const float* __restrict__ beta,
                                                   const int* __restrict__ batch,
                                                   float* __restrict__ pooled,
                                                   short* __restrict__ C, int N) {
    __shared__ float s_aux[256];           // STATS: sum|sq ; BN: scale|shift
    __shared__ short c_tile[4][32 * TSTR]; // per-wave 32-row C staging, padded stride
    __shared__ float s_pool[GSPAN][NFEAT];
    int tid = threadIdx.x;
    int wave = tid >> 6, lane = tid & 63;
    int quad = lane >> 4, l16 = lane & 15;
    int row_base = blockIdx.x * 128 + wave * 32;

    int gbase = 0;
    if constexpr (POOL) {
        int first = blockIdx.x * 128;
        gbase = (first < N) ? batch[first] : 0;
        for (int i = tid; i < GSPAN * NFEAT; i += 256) s_pool[i >> 7][i & 127] = 0.f;
    }
    if constexpr (STATS) s_aux[tid] = 0.f;
    if constexpr (BN_RELU_IN) {
        if (tid < NFEAT) {
            float mean = stats[tid] / (float)N;
            float var = stats[NFEAT + tid] / (float)N - mean * mean;
            float inv = rsqrtf(var + BN_EPS);
            float sc = gamma[tid] * inv;
            s_aux[tid] = sc;
            s_aux[NFEAT + tid] = beta[tid] - mean * sc;
        }
    }
    if constexpr (STATS || BN_RELU_IN || POOL) __syncthreads();

    f32x4 acc[2][8];
#pragma unroll
    for (int i = 0; i < 2; i++)
#pragma unroll
        for (int j = 0; j < 8; j++) acc[i][j] = (f32x4){0.f, 0.f, 0.f, 0.f};

    const short* af = A + ((size_t)(blockIdx.x * 8 + wave * 2) * 4) * 512;

#pragma unroll
    for (int kc = 0; kc < 4; ++kc) {
        bf16x8 a0 = *(const bf16x8*)(af + (size_t)kc * 512 + lane * 8);
        bf16x8 a1 = *(const bf16x8*)(af + (size_t)(4 + kc) * 512 + lane * 8);
        if constexpr (BN_RELU_IN) {
            int koff = kc * 32 + quad * 8;
#pragma unroll
            for (int j = 0; j < 8; j++) {
                float sc = s_aux[koff + j];
                float sh = s_aux[NFEAT + koff + j];
                a0[j] = f2bf(fmaxf(bf2f(a0[j]) * sc + sh, 0.f));
                a1[j] = f2bf(fmaxf(bf2f(a1[j]) * sc + sh, 0.f));
            }
        }
        const short* wp = Wf + ((size_t)(kc * 8) * 64 + lane) * 8;
#pragma unroll
        for (int ct = 0; ct < 8; ++ct) {
            bf16x8 b = *(const bf16x8*)(wp + (size_t)ct * 64 * 8);
            acc[0][ct] = __builtin_amdgcn_mfma_f32_16x16x32_bf16(a0, b, acc[0][ct], 0, 0, 0);
            acc[1][ct] = __builtin_amdgcn_mfma_f32_16x16x32_bf16(a1, b, acc[1][ct], 0, 0, 0);
        }
    }

    // graph index per (rt,reg) row, hoisted (POOL only)
    int dg[8];
    if constexpr (POOL) {
#pragma unroll
        for (int rt = 0; rt < 2; ++rt)
#pragma unroll
            for (int reg = 0; reg < 4; ++reg) {
                int row = row_base + rt * 16 + quad * 4 + reg;
                dg[rt * 4 + reg] = (row < N) ? (batch[row] - gbase) : -1;
            }
    }

    // C/D layout: col = ct*16 + l16, local row = rt*16 + quad*4 + reg
    short* tile = &c_tile[wave][0];
    int row2 = lane >> 1, half = lane & 1;
#pragma unroll
    for (int ct = 0; ct < 8; ++ct) {
        int col = ct * 16 + l16;
        float bv = bias[col];
        float ls = 0.f, ls2 = 0.f;
        int cg = -1;
        float ps = 0.f;
#pragma unroll
        for (int rt = 0; rt < 2; ++rt) {
#pragma unroll
            for (int reg = 0; reg < 4; ++reg) {
                int lrow = rt * 16 + quad * 4 + reg;
                float v = acc[rt][ct][reg] + bv;
                if constexpr (RELU_OUT) v = fmaxf(v, 0.f);
                if constexpr (STATS) {
                    if (row_base + lrow < N) { ls += v; ls2 += v * v; }
                }
                if constexpr (POOL) {
                    int d = dg[rt * 4 + reg];
                    if (d != cg) {
                        if (cg >= 0) atomicAdd(&s_pool[cg & (GSPAN - 1)][col], ps);
                        cg = d; ps = 0.f;
                    }
                    if (d >= 0) ps += v;
                } else {
                    tile[lrow * TSTR + l16] = f2bf(v);
                }
            }
        }
        if constexpr (POOL) {
            if (cg >= 0) atomicAdd(&s_pool[cg & (GSPAN - 1)][col], ps);
        }
        if constexpr (STATS) {
            ls += __shfl_xor(ls, 16);
            ls += __shfl_xor(ls, 32);
            ls2 += __shfl_xor(ls2, 16);
            ls2 += __shfl_xor(ls2, 32);
            if (quad == 0) {
                atomicAdd(&s_aux[col], ls);
                atomicAdd(&s_aux[NFEAT + col], ls2);
            }
        }
        if constexpr (!POOL) {
            // wave-private tile: same-wave DS ordering suffices, no barrier
            uint4 val = *(const uint4*)(tile + row2 * TSTR + half * 8);
            int grow = row_base + row2;
            if (grow < N) {
                int col0 = ct * 16 + half * 8;
                if constexpr (FRAG_OUT) {
                    size_t addr = ((size_t)(grow >> 4) * 4 + (col0 >> 5)) * 512 +
                                  (size_t)((((col0 >> 3) & 3) * 16 + (grow & 15)) * 8);
                    *(uint4*)(C + addr) = val;
                } else {
                    *(uint4*)(C + (size_t)grow * NFEAT + col0) = val;
                }
            }
        }
    }

    if constexpr (STATS) {
        __syncthreads();
        if (tid < NFEAT) {
            atomicAdd(&stats[tid], s_aux[tid]);
            atomicAdd(&stats[NFEAT + tid], s_aux[NFEAT + tid]);
        }
    }
    if constexpr (POOL) {
        __syncthreads();
        for (int i = tid; i < GSPAN * NFEAT; i += 256) {
            float v = s_pool[i >> 7][i & 127];
            if (v != 0.f) {
                int gg = gbase + (i >> 7);
                if (gg < NGRAPHS) atomicAdd(&pooled[gg * NFEAT + (i & 127)], v);
            }
        }
    }
}

__global__ void k_final(const float* __restrict__ pooled, const float* __restrict__ Wl,
                        const float* __restrict__ bl, float* __restrict__ out) {
    int idx = blockIdx.x * blockDim.x + threadIdx.x;
    if (idx >= NGRAPHS * TGRAPH) return;
    int g = idx / TGRAPH, t = idx % TGRAPH;
    const float* p = pooled + (size_t)g * NFEAT;
    float acc = bl[t];
#pragma unroll 16
    for (int k = 0; k < NFEAT; ++k) acc += p[k] * Wl[k * TGRAPH + t];
    out[idx] = acc;
}

extern "C" void kernel_launch(void* const* d_in, const int* in_sizes, int n_in,
                              void* d_out, int out_size, void* d_ws, size_t ws_size,
                              hipStream_t stream) {
    const float* x = (const float*)d_in[0];
    const int* ei = (const int*)d_in[1];
    const int* batch = (const int*)d_in[2];
    const float* W1a = (const float*)d_in[3];
    const float* b1a = (const float*)d_in[4];
    const float* g1 = (const float*)d_in[5];
    const float* bt1 = (const float*)d_in[6];
    const float* W1b = (const float*)d_in[7];
    const float* b1b = (const float*)d_in[8];
    const float* W2a = (const float*)d_in[9];
    const float* b2a = (const float*)d_in[10];
    const float* g2 = (const float*)d_in[11];
    const float* bt2 = (const float*)d_in[12];
    const float* W2b = (const float*)d_in[13];
    const float* b2b = (const float*)d_in[14];
    const float* Wl = (const float*)d_in[15];
    const float* bl = (const float*)d_in[16];
    float* out = (float*)d_out;

    int N = in_sizes[2];
    int E = in_sizes[1] / 2;
    int nb = (N + 511) >> 9;
    const int* src = ei;
    const int* dst = ei + E;

    int gemmBlocks = (N + 127) / 128;
    int padRows = gemmBlocks * 128;

    char* ws = (char*)d_ws;
    size_t off = 0;
    auto alloc = [&](size_t bytes) -> void* {
        void* p = ws + off;
        off = (off + bytes + 255) & ~(size_t)255;
        return p;
    };
    short* xbf = (short*)alloc((size_t)N * NFEAT * 2);        // row-major (gather input)
    short* ag = (short*)alloc((size_t)padRows * NFEAT * 2);   // frag layout
    short* ybf = (short*)alloc((size_t)padRows * NFEAT * 2);  // frag layout
    short* hbf = (short*)alloc((size_t)N * NFEAT * 2);        // row-major (gather input)
    short* Wf = (short*)alloc((size_t)4 * 16384 * 2);
    int* adj = (int*)alloc((size_t)E * 4);
    int2* binned = (int2*)alloc((size_t)E * 8);
    int* rowptr = (int*)alloc((size_t)(N + 1) * 4);
    int* bbase = (int*)alloc(257 * 4);
    int* cur256 = (int*)alloc(256 * 4);
    // zero-region: bhist + stats1 + stats2 + pooled
    int* bhist = (int*)alloc(256 * 4);
    float* stats1 = (float*)alloc(256 * 4);
    float* stats2 = (float*)alloc(256 * 4);
    float* pooled = (float*)alloc((size_t)NGRAPHS * NFEAT * 4);
    size_t zbytes = (char*)(pooled + (size_t)NGRAPHS * NFEAT) - (char*)bhist;

    hipMemsetAsync(bhist, 0, zbytes, stream);

    // ---- merged hist + dtype prep (one dispatch), then CSR chain ----
    int n4 = N * NFEAT / 4;
    int prepTot = n4 + 4 * 16384;
    int hb = 784;
    k_prep_hist<<<hb + (prepTot + 255) / 256, 256, 0, stream>>>(
        dst, bhist, E, hb, x, xbf, W1a, W1b, W2a, W2b, Wf, n4);
    k_bucket_scan<<<1, 256, 0, stream>>>(bhist, bbase, cur256, E);
    k_bin_scatter<<<(E + BIN_CHUNK - 1) / BIN_CHUNK, 256, 0, stream>>>(src, dst, cur256, binned, E);
    k_bucket_csr<<<nb, 512, 0, stream>>>(binned, bbase, rowptr, adj, N, E, nb);

    int aggBlocks = (N + 3) / 4;  // one wave per node

    // ---- layer 1 ----
    k_aggregate_v4<<<aggBlocks, 256, 0, stream>>>(xbf, rowptr, adj, ag, N);
    k_gemm_mfma<false, false, true, true, false><<<gemmBlocks, 256, 0, stream>>>(
        ag, Wf + 0 * 16384, b1a, stats1, nullptr, nullptr, nullptr, nullptr, ybf, N);
    k_gemm_mfma<true, true, false, false, false><<<gemmBlocks, 256, 0, stream>>>(
        ybf, Wf + 1 * 16384, b1b, stats1, g1, bt1, nullptr, nullptr, hbf, N);

    // ---- layer 2 (GEMM-b pools directly) ----
    k_aggregate_v4<<<aggBlocks, 256, 0, stream>>>(hbf, rowptr, adj, ag, N);
    k_gemm_mfma<false, false, true, true, false><<<gemmBlocks, 256, 0, stream>>>(
        ag, Wf + 2 * 16384, b2a, stats2, nullptr, nullptr, nullptr, nullptr, ybf, N);
    k_gemm_mfma<true, true, false, false, true><<<gemmBlocks, 256, 0, stream>>>(
        ybf, Wf + 3 * 16384, b2b, stats2, g2, bt2, batch, pooled, nullptr, N);

    // ---- classifier ----
    k_final<<<(NGRAPHS * TGRAPH + 255) / 256, 256, 0, stream>>>(pooled, Wl, bl, out);
}